// Round 5
// baseline (1158.501 us; speedup 1.0000x reference)
//
#include <hip/hip_runtime.h>
#include <hip/hip_bf16.h>
#include <stdint.h>

// GRU-D fused cell. B=16384, E=H=1024.
// bf16 MFMA GEMMs (m97 128x128 tile, BK=32, global_load_lds w16), fused decay
// epilogues. R4/R5: (1) LDS-transposed float4 epilogue (was scattered dword —
// EPI-0 ran at 1.75 TB/s); (2) bijective XCD block swizzle (m204) for L2
// panel reuse; (3) sEpi row stride 76 (72 gave 4-way bank conflict on the
// scatter writes). fp32 pre-activations in batch-chunks sized to fit d_ws;
// h(fp32) lives in d_out (gates reads then overwrites elementwise).

#define Bn 16384
#define En 1024
#define Hn 1024

typedef __bf16 bf16x8 __attribute__((ext_vector_type(8)));
typedef float f32x4 __attribute__((ext_vector_type(4)));
typedef unsigned short u16x8 __attribute__((ext_vector_type(8)));
typedef unsigned short u16x4 __attribute__((ext_vector_type(4)));

__device__ __forceinline__ void gload_lds16(const void* g, void* l) {
  __builtin_amdgcn_global_load_lds(
      (const __attribute__((address_space(1))) void*)g,
      (__attribute__((address_space(3))) void*)l, 16, 0, 0);
}

__device__ __forceinline__ unsigned short f2bf(float f) {
  __hip_bfloat16 h = __float2bfloat16(f);
  return __builtin_bit_cast(unsigned short, h);
}

// ---------------- conversion kernels ----------------

__global__ void conv_f32_bf16(const float* __restrict__ in,
                              unsigned short* __restrict__ out, long n) {
  long stride = (long)gridDim.x * blockDim.x;
  for (long i = (long)blockIdx.x * blockDim.x + threadIdx.x; i * 8 < n; i += stride) {
    long b = i * 8;
    float4 a0 = *(const float4*)&in[b];
    float4 a1 = *(const float4*)&in[b + 4];
    u16x8 o;
    o[0] = f2bf(a0.x); o[1] = f2bf(a0.y); o[2] = f2bf(a0.z); o[3] = f2bf(a0.w);
    o[4] = f2bf(a1.x); o[5] = f2bf(a1.y); o[6] = f2bf(a1.z); o[7] = f2bf(a1.w);
    *(u16x8*)&out[b] = o;
  }
}

// x_mask -> bf16 into right half of U ([B][2048], cols 1024..2047)
__global__ void conv_mask_k(const float* __restrict__ in,
                            unsigned short* __restrict__ U) {
  long n = (long)Bn * En;
  long stride = (long)gridDim.x * blockDim.x;
  for (long i = (long)blockIdx.x * blockDim.x + threadIdx.x; i * 8 < n; i += stride) {
    long b = i * 8;
    long row = b >> 10;
    int col = (int)(b & 1023);
    float4 a0 = *(const float4*)&in[b];
    float4 a1 = *(const float4*)&in[b + 4];
    u16x8 o;
    o[0] = f2bf(a0.x); o[1] = f2bf(a0.y); o[2] = f2bf(a0.z); o[3] = f2bf(a0.w);
    o[4] = f2bf(a1.x); o[5] = f2bf(a1.y); o[6] = f2bf(a1.z); o[7] = f2bf(a1.w);
    *(u16x8*)&U[row * 2048 + 1024 + col] = o;
  }
}

// out[C][R] (bf16) = in[R][C] (f32) transposed
__global__ void transpose_conv(const float* __restrict__ in,
                               unsigned short* __restrict__ out, int R, int C) {
  __shared__ float tile[32][33];
  int bc = blockIdx.x * 32, br = blockIdx.y * 32;
  int tx = threadIdx.x, ty = threadIdx.y;
#pragma unroll
  for (int i = 0; i < 32; i += 8)
    tile[ty + i][tx] = in[(size_t)(br + ty + i) * C + (bc + tx)];
  __syncthreads();
#pragma unroll
  for (int i = 0; i < 32; i += 8)
    out[(size_t)(bc + ty + i) * R + (br + tx)] = f2bf(tile[tx][ty + i]);
}

// ---------------- GEMM: C[M,N] = A[M,K] * Bt[N,K]^T (bf16 in, f32 acc) -----
// 128x128 tile, BK=32, 4 waves (each 64x64), mfma_f32_16x16x32_bf16.
// 1D grid + bijective XCD swizzle; bx (M-block) fast -> XCD chunk shares
// B-panel. Epilogue transposes acc through per-wave LDS -> float4 I/O.
// EPI 0: delta_x epilogue -> x_t bf16 into U (ldo=2048)
// EPI 1: delta_h epilogue -> h bf16 (ob) + h f32 (of)
// EPI 2: plain f32 store (of, ldo)

template <int EPI>
__launch_bounds__(256)
__global__ void gemm_nt(const unsigned short* __restrict__ A,
                        const unsigned short* __restrict__ Bt,
                        int gridX, int gridY, int K,
                        const float* __restrict__ bias,
                        const float* __restrict__ e0, const float* __restrict__ e1,
                        const float* __restrict__ e2, const float* __restrict__ e3,
                        unsigned short* __restrict__ ob, float* __restrict__ of,
                        int ldo) {
  __shared__ unsigned short sA[128 * 32];
  __shared__ unsigned short sB[128 * 32];
  __shared__ float sEpi[4][16][76];  // per-wave transpose staging (19 KiB)

  // bijective XCD swizzle (m204): contiguous work chunk per XCD
  const int nwg = gridX * gridY;
  const int q = nwg >> 3, r = nwg & 7;
  const int xcd = (int)blockIdx.x & 7, pos = (int)blockIdx.x >> 3;
  const int wg = (xcd < r ? xcd * (q + 1) : r * (q + 1) + (xcd - r) * q) + pos;
  const int by = wg / gridX;         // N-block (slow => shared within chunk)
  const int bx = wg - by * gridX;    // M-block (fast)

  const int t = threadIdx.x;
  const int lane = t & 63;
  const int w = t >> 6;
  const int wr = w >> 1, wc = w & 1;
  const int rowA0 = bx * 128, colB0 = by * 128;

  f32x4 acc[4][4] = {};

  // staging: thread t stages 16B at LDS offset t*16 then (t+256)*16
  const int fe0 = t * 8;          // elems
  const int r0 = fe0 >> 5, c0e = fe0 & 31;
  const int fe1 = (t + 256) * 8;
  const int r1 = fe1 >> 5, c1e = fe1 & 31;

  const unsigned short* Ab0 = A + (size_t)(rowA0 + r0) * K + c0e;
  const unsigned short* Ab1 = A + (size_t)(rowA0 + r1) * K + c1e;
  const unsigned short* Bb0 = Bt + (size_t)(colB0 + r0) * K + c0e;
  const unsigned short* Bb1 = Bt + (size_t)(colB0 + r1) * K + c1e;
  unsigned short* sA0 = &sA[t * 8];
  unsigned short* sA1 = &sA[(t + 256) * 8];
  unsigned short* sB0 = &sB[t * 8];
  unsigned short* sB1 = &sB[(t + 256) * 8];

  const int arow = lane & 15;
  const int kh = (lane >> 4) * 8;

  for (int k0 = 0; k0 < K; k0 += 32) {
    gload_lds16(Ab0 + k0, sA0);
    gload_lds16(Ab1 + k0, sA1);
    gload_lds16(Bb0 + k0, sB0);
    gload_lds16(Bb1 + k0, sB1);
    __syncthreads();
    bf16x8 af[4], bfr[4];
#pragma unroll
    for (int m = 0; m < 4; ++m)
      af[m] = *(const bf16x8*)&sA[(wr * 64 + m * 16 + arow) * 32 + kh];
#pragma unroll
    for (int n = 0; n < 4; ++n)
      bfr[n] = *(const bf16x8*)&sB[(wc * 64 + n * 16 + arow) * 32 + kh];
#pragma unroll
    for (int m = 0; m < 4; ++m)
#pragma unroll
      for (int n = 0; n < 4; ++n)
        acc[m][n] = __builtin_amdgcn_mfma_f32_16x16x32_bf16(af[m], bfr[n], acc[m][n], 0, 0, 0);
    __syncthreads();
  }

  // ---- epilogue via per-wave LDS transpose (no cross-wave sharing) ----
  // MFMA C/D layout: col=lane&15, row=(lane>>4)*4+j  [m89]
  const int ccol = lane & 15;
  const int crow0 = (lane >> 4) * 4;
  const int rr0 = lane >> 4;        // 0..3: row-in-group for readback
  const int cc0 = (lane & 15) * 4;  // 0..60: col for readback

#pragma unroll
  for (int m = 0; m < 4; ++m) {
#pragma unroll
    for (int n = 0; n < 4; ++n)
#pragma unroll
      for (int j = 0; j < 4; ++j)
        sEpi[w][crow0 + j][n * 16 + ccol] = acc[m][n][j];
    // same-wave DS ops are processed in order; compiler inserts lgkmcnt waits
#pragma unroll
    for (int v = 0; v < 4; ++v) {
      const int rr = v * 4 + rr0;
      const int grow = rowA0 + wr * 64 + m * 16 + rr;
      const int gcol = colB0 + wc * 64 + cc0;
      float4 vv = *(const float4*)&sEpi[w][rr][cc0];
      const float* vp = (const float*)&vv;
      if constexpr (EPI == 0) {
        float4 bi = *(const float4*)&bias[gcol];
        size_t idx = (size_t)grow * 1024 + gcol;
        float4 xv = *(const float4*)&e0[idx];
        float4 mv = *(const float4*)&e1[idx];
        float4 xl = *(const float4*)&e2[idx];
        float4 xm = *(const float4*)&e3[idx];
        u16x4 o;
#pragma unroll
        for (int c = 0; c < 4; ++c) {
          float dx = expf(-fmaxf(vp[c] + ((const float*)&bi)[c], 0.f));
          float xvv = ((const float*)&xv)[c], mvv = ((const float*)&mv)[c];
          float xlv = ((const float*)&xl)[c], xmv = ((const float*)&xm)[c];
          float xt = mvv * xvv + (1.f - mvv) * (dx * xlv + (1.f - dx) * xmv);
          o[c] = f2bf(xt);
        }
        *(u16x4*)&ob[(size_t)grow * ldo + gcol] = o;
      } else if constexpr (EPI == 1) {
        float4 bi = *(const float4*)&bias[gcol];
        size_t idx = (size_t)grow * 1024 + gcol;
        float4 hv = *(const float4*)&e0[idx];
        u16x4 o;
        float4 of4;
#pragma unroll
        for (int c = 0; c < 4; ++c) {
          float dh = expf(-fmaxf(vp[c] + ((const float*)&bi)[c], 0.f));
          float hval = dh * ((const float*)&hv)[c];
          o[c] = f2bf(hval);
          ((float*)&of4)[c] = hval;
        }
        *(u16x4*)&ob[(size_t)grow * ldo + gcol] = o;
        *(float4*)&of[(size_t)grow * ldo + gcol] = of4;
      } else {
        *(float4*)&of[(size_t)grow * (size_t)ldo + gcol] = vv;
      }
    }
  }
}

// ---------------- gates (per batch-chunk) ----------------
__device__ __forceinline__ float sigm(float x) { return 1.f / (1.f + expf(-x)); }

// Hf may alias out (elementwise read-then-write, same index).
__global__ void gates_k(const float* __restrict__ Gi, const float* __restrict__ Gh,
                        const float* Hf, const float* __restrict__ b_ih,
                        const float* __restrict__ b_hh, float* out,
                        int rows) {
  long n4 = (long)rows * Hn / 4;
  long stride = (long)gridDim.x * blockDim.x;
  for (long i4 = (long)blockIdx.x * blockDim.x + threadIdx.x; i4 < n4; i4 += stride) {
    long i = i4 * 4;
    long row = i >> 10;
    int col = (int)(i & 1023);
    const float* gi = Gi + row * 3072 + col;
    const float* gh = Gh + row * 3072 + col;
    float4 ir = *(const float4*)(gi);
    float4 iz = *(const float4*)(gi + 1024);
    float4 in_ = *(const float4*)(gi + 2048);
    float4 hr = *(const float4*)(gh);
    float4 hz = *(const float4*)(gh + 1024);
    float4 hn = *(const float4*)(gh + 2048);
    float4 bir = *(const float4*)&b_ih[col];
    float4 biz = *(const float4*)&b_ih[1024 + col];
    float4 bin_ = *(const float4*)&b_ih[2048 + col];
    float4 bhr = *(const float4*)&b_hh[col];
    float4 bhz = *(const float4*)&b_hh[1024 + col];
    float4 bhn = *(const float4*)&b_hh[2048 + col];
    float4 hv = *(const float4*)&Hf[i];
    float4 o;
#pragma unroll
    for (int c = 0; c < 4; ++c) {
      float r0 = sigm(((const float*)&ir)[c] + ((const float*)&bir)[c] +
                      ((const float*)&hr)[c] + ((const float*)&bhr)[c]);
      float z0 = sigm(((const float*)&iz)[c] + ((const float*)&biz)[c] +
                      ((const float*)&hz)[c] + ((const float*)&bhz)[c]);
      float nn = tanhf(((const float*)&in_)[c] + ((const float*)&bin_)[c] +
                       r0 * (((const float*)&hn)[c] + ((const float*)&bhn)[c]));
      ((float*)&o)[c] = (1.f - z0) * nn + z0 * ((const float*)&hv)[c];
    }
    *(float4*)&out[i] = o;
  }
}

// ---------------- launch ----------------

extern "C" void kernel_launch(void* const* d_in, const int* in_sizes, int n_in,
                              void* d_out, int out_size, void* d_ws, size_t ws_size,
                              hipStream_t stream) {
  const float* x     = (const float*)d_in[0];
  const float* xmask = (const float*)d_in[1];
  const float* delta = (const float*)d_in[2];
  const float* xlast = (const float*)d_in[3];
  const float* xmean = (const float*)d_in[4];
  const float* hs    = (const float*)d_in[5];
  const float* gx_w  = (const float*)d_in[6];
  const float* gx_b  = (const float*)d_in[7];
  const float* gh_w  = (const float*)d_in[8];
  const float* gh_b  = (const float*)d_in[9];
  const float* w_ih  = (const float*)d_in[10];
  const float* b_ih  = (const float*)d_in[11];
  const float* w_hh  = (const float*)d_in[12];
  const float* b_hh  = (const float*)d_in[13];
  float* out = (float*)d_out;

  char* ws = (char*)d_ws;
  size_t off = 0;
  auto alloc = [&](size_t bytes) {
    char* p = ws + off;
    off += (bytes + 255) & ~(size_t)255;
    return p;
  };
  unsigned short* delta_bf = (unsigned short*)alloc((size_t)Bn * En * 2);        // 32 MiB
  unsigned short* U        = (unsigned short*)alloc((size_t)Bn * 2 * En * 2);    // 64 MiB  [x_t | mask]
  unsigned short* Hbf      = (unsigned short*)alloc((size_t)Bn * Hn * 2);        // 32 MiB
  unsigned short* gxw_bf   = (unsigned short*)alloc((size_t)En * En * 2);        //  2 MiB
  unsigned short* ghw_bf   = (unsigned short*)alloc((size_t)En * En * 2);        //  2 MiB
  unsigned short* wihT     = (unsigned short*)alloc((size_t)3 * Hn * 2 * En * 2);// 12 MiB [3072][2048]
  unsigned short* whhT     = (unsigned short*)alloc((size_t)3 * Hn * Hn * 2);    //  6 MiB [3072][1024]
  float*          Hf32     = out;  // d_out doubles as fp32 h storage (64 MiB)

  // pick chunk count so 2 fp32 [CROWS][3072] buffers fit the remaining ws
  int nchunk = 64;
  for (int c = 4; c <= 64; c *= 2) {
    size_t need = off + 2ull * (Bn / c) * 3 * Hn * 4 + 512;
    if (need <= ws_size) { nchunk = c; break; }
  }
  const int CROWS = Bn / nchunk;
  float* GiC = (float*)alloc((size_t)CROWS * 3 * Hn * 4);
  float* GhC = (float*)alloc((size_t)CROWS * 3 * Hn * 4);

  conv_f32_bf16<<<2048, 256, 0, stream>>>(delta, delta_bf, (long)Bn * En);
  conv_f32_bf16<<<512, 256, 0, stream>>>(gx_w, gxw_bf, (long)En * En);
  conv_f32_bf16<<<512, 256, 0, stream>>>(gh_w, ghw_bf, (long)En * En);
  conv_mask_k<<<2048, 256, 0, stream>>>(xmask, U);
  transpose_conv<<<dim3(3 * Hn / 32, 2 * En / 32), dim3(32, 8), 0, stream>>>(w_ih, wihT, 2 * En, 3 * Hn);
  transpose_conv<<<dim3(3 * Hn / 32, Hn / 32), dim3(32, 8), 0, stream>>>(w_hh, whhT, Hn, 3 * Hn);

  // delta_x GEMM -> x_t into U[:, :1024]   (grid: 128 M-blocks x 8 N-blocks)
  gemm_nt<0><<<Bn / 128 * (En / 128), 256, 0, stream>>>(
      delta_bf, gxw_bf, Bn / 128, En / 128, En, gx_b, x, xmask, xlast, xmean, U,
      nullptr, 2 * En);
  // delta_h GEMM -> h (bf16 into Hbf, f32 into out)
  gemm_nt<1><<<Bn / 128 * (Hn / 128), 256, 0, stream>>>(
      delta_bf, ghw_bf, Bn / 128, Hn / 128, En, gh_b, hs, nullptr, nullptr, nullptr,
      Hbf, Hf32, Hn);

  // per-chunk: Gi, Gh, gates
  for (int c = 0; c < nchunk; ++c) {
    const unsigned short* Uc = U + (size_t)c * CROWS * 2 * En;
    const unsigned short* Hc = Hbf + (size_t)c * CROWS * Hn;
    const float* Hfc = Hf32 + (size_t)c * CROWS * Hn;
    float* outc = out + (size_t)c * CROWS * Hn;
    gemm_nt<2><<<CROWS / 128 * (3 * Hn / 128), 256, 0, stream>>>(
        Uc, wihT, CROWS / 128, 3 * Hn / 128, 2 * En, nullptr, nullptr, nullptr,
        nullptr, nullptr, nullptr, GiC, 3 * Hn);
    gemm_nt<2><<<CROWS / 128 * (3 * Hn / 128), 256, 0, stream>>>(
        Hc, whhT, CROWS / 128, 3 * Hn / 128, Hn, nullptr, nullptr, nullptr,
        nullptr, nullptr, nullptr, GhC, 3 * Hn);
    gates_k<<<2048, 256, 0, stream>>>(GiC, GhC, Hfc, b_ih, b_hh, outc, CROWS);
  }
}

// Round 10
// 1108.945 us; speedup vs baseline: 1.0447x; 1.0447x over previous
//
#include <hip/hip_runtime.h>
#include <hip/hip_bf16.h>
#include <stdint.h>

// GRU-D fused cell. B=16384, E=H=1024.
// R10 = R9 resubmit (acquisition timeout; bisect never ran).
// R6/R7/R8 all fail with IDENTICAL absmax 2.41 despite three different gates
// implementations -> bug is upstream in the R6-introduced {merged decay_gemm,
// gw2 stack, bsum}. This round: R5's exact PASSING downstream (no-bias Gi/Gh
// GEMMs + gates_k with full bias adds, bsum deleted) + merged decay_gemm as
// the single experimental variable. Pass => decay innocent, bsum-side guilty.
// Fail w/ 2.409180 => decay_gemm definitively guilty; revert to split decay.

#define Bn 16384
#define En 1024
#define Hn 1024

typedef __bf16 bf16x8 __attribute__((ext_vector_type(8)));
typedef float f32x4 __attribute__((ext_vector_type(4)));
typedef unsigned short u16x8 __attribute__((ext_vector_type(8)));
typedef unsigned short u16x4 __attribute__((ext_vector_type(4)));

__device__ __forceinline__ void gload_lds16(const void* g, void* l) {
  __builtin_amdgcn_global_load_lds(
      (const __attribute__((address_space(1))) void*)g,
      (__attribute__((address_space(3))) void*)l, 16, 0, 0);
}

__device__ __forceinline__ unsigned short f2bf(float f) {
  __hip_bfloat16 h = __float2bfloat16(f);
  return __builtin_bit_cast(unsigned short, h);
}

__device__ __forceinline__ float sigm(float x) { return 1.f / (1.f + expf(-x)); }

// bijective XCD swizzle (m204); returns (bx, by) with by FAST
__device__ __forceinline__ void swz(int bid, int gridY, int nwg, int* bx, int* by) {
  int q = nwg >> 3, r = nwg & 7;
  int xcd = bid & 7, pos = bid >> 3;
  int wg = (xcd < r ? xcd * (q + 1) : r * (q + 1) + (xcd - r) * q) + pos;
  *bx = wg / gridY;
  *by = wg - *bx * gridY;
}

// ---------------- small prep kernels ----------------

__global__ void conv_f32_bf16(const float* __restrict__ in,
                              unsigned short* __restrict__ out, long n) {
  long stride = (long)gridDim.x * blockDim.x;
  for (long i = (long)blockIdx.x * blockDim.x + threadIdx.x; i * 8 < n; i += stride) {
    long b = i * 8;
    float4 a0 = *(const float4*)&in[b];
    float4 a1 = *(const float4*)&in[b + 4];
    u16x8 o;
    o[0] = f2bf(a0.x); o[1] = f2bf(a0.y); o[2] = f2bf(a0.z); o[3] = f2bf(a0.w);
    o[4] = f2bf(a1.x); o[5] = f2bf(a1.y); o[6] = f2bf(a1.z); o[7] = f2bf(a1.w);
    *(u16x8*)&out[b] = o;
  }
}

// out[C][R] (bf16) = in[R][C] (f32) transposed
__global__ void transpose_conv(const float* __restrict__ in,
                               unsigned short* __restrict__ out, int R, int C) {
  __shared__ float tile[32][33];
  int bc = blockIdx.x * 32, br = blockIdx.y * 32;
  int tx = threadIdx.x, ty = threadIdx.y;
#pragma unroll
  for (int i = 0; i < 32; i += 8)
    tile[ty + i][tx] = in[(size_t)(br + ty + i) * C + (bc + tx)];
  __syncthreads();
#pragma unroll
  for (int i = 0; i < 32; i += 8)
    out[(size_t)(bc + ty + i) * R + (br + tx)] = f2bf(tile[tx][ty + i]);
}

// ---------------- decay GEMM: [B,1024] @ [2048,1024]^T (EXPERIMENTAL) ------
// cols 0..1023: delta_x -> x_t (bf16) + mask (bf16) into U[B][2048]
// cols 1024..2047: delta_h -> h bf16 (Hbf) + h f32 (outF)
__launch_bounds__(256)
__global__ void decay_gemm(const unsigned short* __restrict__ A,
                           const unsigned short* __restrict__ Bt,
                           const float* __restrict__ gx_b, const float* __restrict__ gh_b,
                           const float* __restrict__ x, const float* __restrict__ xmask,
                           const float* __restrict__ xlast, const float* __restrict__ xmean,
                           const float* __restrict__ hs,
                           unsigned short* __restrict__ U, unsigned short* __restrict__ Hbf,
                           float* __restrict__ outF) {
  __shared__ unsigned short sA[128 * 32];
  __shared__ unsigned short sB[128 * 32];
  __shared__ float sEpi[4][16][76];
  const int K = 1024;

  int bx, by;
  swz((int)blockIdx.x, 16, 128 * 16, &bx, &by);

  const int t = threadIdx.x;
  const int lane = t & 63;
  const int w = t >> 6;
  const int wr = w >> 1, wc = w & 1;
  const int rowA0 = bx * 128, colB0 = by * 128;

  f32x4 acc[4][4] = {};

  const int fe0 = t * 8, r0 = fe0 >> 5, c0e = fe0 & 31;
  const int fe1 = (t + 256) * 8, r1 = fe1 >> 5, c1e = fe1 & 31;
  const unsigned short* Ab0 = A + (size_t)(rowA0 + r0) * K + c0e;
  const unsigned short* Ab1 = A + (size_t)(rowA0 + r1) * K + c1e;
  const unsigned short* Bb0 = Bt + (size_t)(colB0 + r0) * K + c0e;
  const unsigned short* Bb1 = Bt + (size_t)(colB0 + r1) * K + c1e;
  unsigned short* sA0 = &sA[t * 8];
  unsigned short* sA1 = &sA[(t + 256) * 8];
  unsigned short* sB0 = &sB[t * 8];
  unsigned short* sB1 = &sB[(t + 256) * 8];

  const int arow = lane & 15;
  const int kh = (lane >> 4) * 8;

  for (int k0 = 0; k0 < K; k0 += 32) {
    gload_lds16(Ab0 + k0, sA0);
    gload_lds16(Ab1 + k0, sA1);
    gload_lds16(Bb0 + k0, sB0);
    gload_lds16(Bb1 + k0, sB1);
    __syncthreads();
    bf16x8 af[4], bfr[4];
#pragma unroll
    for (int m = 0; m < 4; ++m)
      af[m] = *(const bf16x8*)&sA[(wr * 64 + m * 16 + arow) * 32 + kh];
#pragma unroll
    for (int n = 0; n < 4; ++n)
      bfr[n] = *(const bf16x8*)&sB[(wc * 64 + n * 16 + arow) * 32 + kh];
#pragma unroll
    for (int m = 0; m < 4; ++m)
#pragma unroll
      for (int n = 0; n < 4; ++n)
        acc[m][n] = __builtin_amdgcn_mfma_f32_16x16x32_bf16(af[m], bfr[n], acc[m][n], 0, 0, 0);
    __syncthreads();
  }

  const int ccol = lane & 15;
  const int crow0 = (lane >> 4) * 4;
  const int rr0 = lane >> 4;
  const int cc0 = (lane & 15) * 4;
  const bool xtPath = (colB0 < 1024);

#pragma unroll
  for (int m = 0; m < 4; ++m) {
#pragma unroll
    for (int n = 0; n < 4; ++n)
#pragma unroll
      for (int j = 0; j < 4; ++j)
        sEpi[w][crow0 + j][n * 16 + ccol] = acc[m][n][j];
#pragma unroll
    for (int v = 0; v < 4; ++v) {
      const int rr = v * 4 + rr0;
      const int grow = rowA0 + wr * 64 + m * 16 + rr;
      const int gcol = colB0 + wc * 64 + cc0;
      float4 vv = *(const float4*)&sEpi[w][rr][cc0];
      const float* vp = (const float*)&vv;
      if (xtPath) {
        float4 bi = *(const float4*)&gx_b[gcol];
        size_t idx = (size_t)grow * 1024 + gcol;
        float4 xv = *(const float4*)&x[idx];
        float4 mv = *(const float4*)&xmask[idx];
        float4 xl = *(const float4*)&xlast[idx];
        float4 xm = *(const float4*)&xmean[idx];
        u16x4 oxt, omk;
#pragma unroll
        for (int c = 0; c < 4; ++c) {
          float dx = expf(-fmaxf(vp[c] + ((const float*)&bi)[c], 0.f));
          float xvv = ((const float*)&xv)[c], mvv = ((const float*)&mv)[c];
          float xlv = ((const float*)&xl)[c], xmv = ((const float*)&xm)[c];
          float xt = mvv * xvv + (1.f - mvv) * (dx * xlv + (1.f - dx) * xmv);
          oxt[c] = f2bf(xt);
          omk[c] = f2bf(mvv);
        }
        *(u16x4*)&U[(size_t)grow * 2048 + gcol] = oxt;
        *(u16x4*)&U[(size_t)grow * 2048 + 1024 + gcol] = omk;
      } else {
        const int col = gcol - 1024;
        float4 bi = *(const float4*)&gh_b[col];
        size_t idx = (size_t)grow * 1024 + col;
        float4 hv = *(const float4*)&hs[idx];
        u16x4 o;
        float4 of4;
#pragma unroll
        for (int c = 0; c < 4; ++c) {
          float dh = expf(-fmaxf(vp[c] + ((const float*)&bi)[c], 0.f));
          float hval = dh * ((const float*)&hv)[c];
          o[c] = f2bf(hval);
          ((float*)&of4)[c] = hval;
        }
        *(u16x4*)&Hbf[idx] = o;
        *(float4*)&outF[idx] = of4;
      }
    }
  }
}

// ---------------- plain NT GEMM -> fp32 C (R5 gemm_nt<2> verbatim) --------
__launch_bounds__(256)
__global__ void gemmC(const unsigned short* __restrict__ A,
                      const unsigned short* __restrict__ Bt,
                      int gridX, int gridY, int K,
                      float* __restrict__ of, int ldo) {
  __shared__ unsigned short sA[128 * 32];
  __shared__ unsigned short sB[128 * 32];
  __shared__ float sEpi[4][16][76];

  // R5's exact swizzle form (by slow over gridX divisor)
  const int nwg = gridX * gridY;
  const int q = nwg >> 3, r = nwg & 7;
  const int xcd = (int)blockIdx.x & 7, pos = (int)blockIdx.x >> 3;
  const int wg = (xcd < r ? xcd * (q + 1) : r * (q + 1) + (xcd - r) * q) + pos;
  const int by = wg / gridX;
  const int bx = wg - by * gridX;

  const int t = threadIdx.x;
  const int lane = t & 63;
  const int w = t >> 6;
  const int wr = w >> 1, wc = w & 1;
  const int rowA0 = bx * 128, colB0 = by * 128;

  f32x4 acc[4][4] = {};

  const int fe0 = t * 8, r0 = fe0 >> 5, c0e = fe0 & 31;
  const int fe1 = (t + 256) * 8, r1 = fe1 >> 5, c1e = fe1 & 31;
  const unsigned short* Ab0 = A + (size_t)(rowA0 + r0) * K + c0e;
  const unsigned short* Ab1 = A + (size_t)(rowA0 + r1) * K + c1e;
  const unsigned short* Bb0 = Bt + (size_t)(colB0 + r0) * K + c0e;
  const unsigned short* Bb1 = Bt + (size_t)(colB0 + r1) * K + c1e;
  unsigned short* sA0 = &sA[t * 8];
  unsigned short* sA1 = &sA[(t + 256) * 8];
  unsigned short* sB0 = &sB[t * 8];
  unsigned short* sB1 = &sB[(t + 256) * 8];

  const int arow = lane & 15;
  const int kh = (lane >> 4) * 8;

  for (int k0 = 0; k0 < K; k0 += 32) {
    gload_lds16(Ab0 + k0, sA0);
    gload_lds16(Ab1 + k0, sA1);
    gload_lds16(Bb0 + k0, sB0);
    gload_lds16(Bb1 + k0, sB1);
    __syncthreads();
    bf16x8 af[4], bfr[4];
#pragma unroll
    for (int m = 0; m < 4; ++m)
      af[m] = *(const bf16x8*)&sA[(wr * 64 + m * 16 + arow) * 32 + kh];
#pragma unroll
    for (int n = 0; n < 4; ++n)
      bfr[n] = *(const bf16x8*)&sB[(wc * 64 + n * 16 + arow) * 32 + kh];
#pragma unroll
    for (int m = 0; m < 4; ++m)
#pragma unroll
      for (int n = 0; n < 4; ++n)
        acc[m][n] = __builtin_amdgcn_mfma_f32_16x16x32_bf16(af[m], bfr[n], acc[m][n], 0, 0, 0);
    __syncthreads();
  }

  const int ccol = lane & 15;
  const int crow0 = (lane >> 4) * 4;
  const int rr0 = lane >> 4;
  const int cc0 = (lane & 15) * 4;

#pragma unroll
  for (int m = 0; m < 4; ++m) {
#pragma unroll
    for (int n = 0; n < 4; ++n)
#pragma unroll
      for (int j = 0; j < 4; ++j)
        sEpi[w][crow0 + j][n * 16 + ccol] = acc[m][n][j];
#pragma unroll
    for (int v = 0; v < 4; ++v) {
      const int rr = v * 4 + rr0;
      const int grow = rowA0 + wr * 64 + m * 16 + rr;
      const int gcol = colB0 + wc * 64 + cc0;
      float4 vv = *(const float4*)&sEpi[w][rr][cc0];
      *(float4*)&of[(size_t)grow * (size_t)ldo + gcol] = vv;
    }
  }
}

// ---------------- gates (R5 verbatim: full bias adds) ----------------
// Hf aliases out (same-index read-then-write).
__global__ void gates_k(const float* __restrict__ Gi, const float* __restrict__ Gh,
                        const float* Hf, const float* __restrict__ b_ih,
                        const float* __restrict__ b_hh, float* out,
                        int rows) {
  long n4 = (long)rows * Hn / 4;
  long stride = (long)gridDim.x * blockDim.x;
  for (long i4 = (long)blockIdx.x * blockDim.x + threadIdx.x; i4 < n4; i4 += stride) {
    long i = i4 * 4;
    long row = i >> 10;
    int col = (int)(i & 1023);
    const float* gi = Gi + row * 3072 + col;
    const float* gh = Gh + row * 3072 + col;
    float4 ir = *(const float4*)(gi);
    float4 iz = *(const float4*)(gi + 1024);
    float4 in_ = *(const float4*)(gi + 2048);
    float4 hr = *(const float4*)(gh);
    float4 hz = *(const float4*)(gh + 1024);
    float4 hn = *(const float4*)(gh + 2048);
    float4 bir = *(const float4*)&b_ih[col];
    float4 biz = *(const float4*)&b_ih[1024 + col];
    float4 bin_ = *(const float4*)&b_ih[2048 + col];
    float4 bhr = *(const float4*)&b_hh[col];
    float4 bhz = *(const float4*)&b_hh[1024 + col];
    float4 bhn = *(const float4*)&b_hh[2048 + col];
    float4 hv = *(const float4*)&Hf[i];
    float4 o;
#pragma unroll
    for (int c = 0; c < 4; ++c) {
      float r0 = sigm(((const float*)&ir)[c] + ((const float*)&bir)[c] +
                      ((const float*)&hr)[c] + ((const float*)&bhr)[c]);
      float z0 = sigm(((const float*)&iz)[c] + ((const float*)&biz)[c] +
                      ((const float*)&hz)[c] + ((const float*)&bhz)[c]);
      float nn = tanhf(((const float*)&in_)[c] + ((const float*)&bin_)[c] +
                       r0 * (((const float*)&hn)[c] + ((const float*)&bhn)[c]));
      ((float*)&o)[c] = (1.f - z0) * nn + z0 * ((const float*)&hv)[c];
    }
    *(float4*)&out[i] = o;
  }
}

// ---------------- launch ----------------

extern "C" void kernel_launch(void* const* d_in, const int* in_sizes, int n_in,
                              void* d_out, int out_size, void* d_ws, size_t ws_size,
                              hipStream_t stream) {
  const float* x     = (const float*)d_in[0];
  const float* xmask = (const float*)d_in[1];
  const float* delta = (const float*)d_in[2];
  const float* xlast = (const float*)d_in[3];
  const float* xmean = (const float*)d_in[4];
  const float* hs    = (const float*)d_in[5];
  const float* gx_w  = (const float*)d_in[6];
  const float* gx_b  = (const float*)d_in[7];
  const float* gh_w  = (const float*)d_in[8];
  const float* gh_b  = (const float*)d_in[9];
  const float* w_ih  = (const float*)d_in[10];
  const float* b_ih  = (const float*)d_in[11];
  const float* w_hh  = (const float*)d_in[12];
  const float* b_hh  = (const float*)d_in[13];
  float* out = (float*)d_out;

  char* ws = (char*)d_ws;
  size_t off = 0;
  auto alloc = [&](size_t bytes) {
    char* p = ws + off;
    off += (bytes + 255) & ~(size_t)255;
    return p;
  };
  unsigned short* delta_bf = (unsigned short*)alloc((size_t)Bn * En * 2);        // 32 MiB
  unsigned short* U        = (unsigned short*)alloc((size_t)Bn * 2 * En * 2);    // 64 MiB [x_t|mask]
  unsigned short* Hbf      = (unsigned short*)alloc((size_t)Bn * Hn * 2);        // 32 MiB
  unsigned short* gw2      = (unsigned short*)alloc((size_t)2 * En * En * 2);    //  4 MiB [gx_w;gh_w]
  unsigned short* wihT     = (unsigned short*)alloc((size_t)3 * Hn * 2 * En * 2);// 12 MiB
  unsigned short* whhT     = (unsigned short*)alloc((size_t)3 * Hn * Hn * 2);    //  6 MiB

  // pick chunk count so TWO fp32 [CROWS][3072] buffers fit remaining ws
  int nchunk = 64;
  for (int c = 4; c <= 64; c *= 2) {
    size_t need = off + 2ull * (Bn / c) * 3 * Hn * 4 + 512;
    if (need <= ws_size) { nchunk = c; break; }
  }
  const int CROWS = Bn / nchunk;
  float* GiC = (float*)alloc((size_t)CROWS * 3 * Hn * 4);
  float* GhC = (float*)alloc((size_t)CROWS * 3 * Hn * 4);

  // prep
  conv_f32_bf16<<<2048, 256, 0, stream>>>(delta, delta_bf, (long)Bn * En);
  conv_f32_bf16<<<512, 256, 0, stream>>>(gx_w, gw2, (long)En * En);
  conv_f32_bf16<<<512, 256, 0, stream>>>(gh_w, gw2 + (size_t)En * En, (long)En * En);
  transpose_conv<<<dim3(3 * Hn / 32, 2 * En / 32), dim3(32, 8), 0, stream>>>(w_ih, wihT, 2 * En, 3 * Hn);
  transpose_conv<<<dim3(3 * Hn / 32, Hn / 32), dim3(32, 8), 0, stream>>>(w_hh, whhT, Hn, 3 * Hn);

  // EXPERIMENTAL: fused decay GEMM (N=2048): x_t+mask -> U, h -> Hbf + out(f32)
  decay_gemm<<<128 * 16, 256, 0, stream>>>(
      delta_bf, gw2, gx_b, gh_b, x, xmask, xlast, xmean, hs, U, Hbf, out);

  // per chunk: Gi (K=2048, raw), Gh (K=1024, raw), gates with full biases (R5)
  for (int c = 0; c < nchunk; ++c) {
    const unsigned short* Uc = U + (size_t)c * CROWS * 2 * En;
    const unsigned short* Hc = Hbf + (size_t)c * CROWS * Hn;
    float* outc = out + (size_t)c * CROWS * Hn;
    gemmC<<<(CROWS / 128) * 24, 256, 0, stream>>>(
        Uc, wihT, CROWS / 128, 24, 2 * En, GiC, 3 * Hn);
    gemmC<<<(CROWS / 128) * 24, 256, 0, stream>>>(
        Hc, whhT, CROWS / 128, 24, Hn, GhC, 3 * Hn);
    gates_k<<<2048, 256, 0, stream>>>(GiC, GhC, outc, b_ih, b_hh, outc, CROWS);
  }
}